// Round 8
// baseline (474.253 us; speedup 1.0000x reference)
//
#include <hip/hip_runtime.h>
#include <math.h>

typedef unsigned short u16;
typedef __attribute__((ext_vector_type(8))) short bf16x8;
typedef __attribute__((ext_vector_type(4))) float f32x4;

#define MFMA16(a,b,c) __builtin_amdgcn_mfma_f32_16x16x32_bf16(a,b,c,0,0,0)

__device__ __forceinline__ u16 f2bf(float f){
  union { float f; unsigned int u; } x; x.f = f;
  unsigned int r = x.u + 0x7fffu + ((x.u >> 16) & 1u);
  return (u16)(r >> 16);
}

__device__ __forceinline__ void gload16(const void* g, void* lds){
  __builtin_amdgcn_global_load_lds(
    (const __attribute__((address_space(1))) unsigned int*)g,
    (__attribute__((address_space(3))) unsigned int*)lds, 16, 0, 0);
}

// ---------------- weights fp32 -> bf16 ---------------------------------------
__global__ __launch_bounds__(256) void cvt_weights(
    const float* __restrict__ wqkv, const float* __restrict__ wo,
    const float* __restrict__ w1, const float* __restrict__ w2,
    u16* __restrict__ o0, u16* __restrict__ o1,
    u16* __restrict__ o2, u16* __restrict__ o3)
{
  int idx = blockIdx.x * 256 + threadIdx.x;   // quad index, 3145728 total
  const float* src; u16* dst;
  if (idx < 786432)                    { src = wqkv; dst = o0; }
  else if ((idx -= 786432) < 262144)   { src = wo;   dst = o1; }
  else if ((idx -= 262144) < 1048576)  { src = w1;   dst = o2; }
  else { idx -= 1048576;                 src = w2;   dst = o3; }
  float4 v = ((const float4*)src)[idx];
  short4 o;
  o.x = (short)f2bf(v.x); o.y = (short)f2bf(v.y);
  o.z = (short)f2bf(v.z); o.w = (short)f2bf(v.w);
  ((short4*)dst)[idx] = o;
}

// ---------------- layernorm over D=1024, out bf16 ----------------------------
template<int MODE>
__global__ __launch_bounds__(256) void ln_kernel(
    const float* __restrict__ s0, const float* __restrict__ s1,
    const float* __restrict__ g, const float* __restrict__ be,
    u16* __restrict__ out)
{
  int row = blockIdx.x, t = threadIdx.x;
  const float* src;
  if (MODE == 1) {
    int b = row >> 11, p = row & 2047;
    src = (p < 1024) ? s0 + ((long)(b*1024 + p))*1024
                     : s1 + ((long)(b*1024 + p - 1024))*1024;
  } else {
    src = s0 + (long)row * 1024;
  }
  float4 v = ((const float4*)src)[t];
  float s  = v.x + v.y + v.z + v.w;
  float ss = v.x*v.x + v.y*v.y + v.z*v.z + v.w*v.w;
  #pragma unroll
  for (int m = 1; m < 64; m <<= 1) { s += __shfl_xor(s, m); ss += __shfl_xor(ss, m); }
  __shared__ float red[8];
  int l = t & 63, w = t >> 6;
  if (l == 0) { red[w*2] = s; red[w*2+1] = ss; }
  __syncthreads();
  s  = red[0] + red[2] + red[4] + red[6];
  ss = red[1] + red[3] + red[5] + red[7];
  float mean = s * (1.0f/1024.0f);
  float var  = ss * (1.0f/1024.0f) - mean*mean;
  float rstd = rsqrtf(var + 1e-5f);
  float4 gv = ((const float4*)g)[t];
  float4 bv = ((const float4*)be)[t];
  short4 o;
  o.x = (short)f2bf((v.x-mean)*rstd*gv.x + bv.x);
  o.y = (short)f2bf((v.y-mean)*rstd*gv.y + bv.y);
  o.z = (short)f2bf((v.z-mean)*rstd*gv.z + bv.z);
  o.w = (short)f2bf((v.w-mean)*rstd*gv.w + bv.w);
  *(short4*)(out + (long)row*1024 + t*4) = o;
}

// ---------------- bf16 GEMM, C = A[M,K] * Bt[N,K]^T, BK=64, double-buffered --
// Stage(t+1) issued BEFORE compute(t); ONE __syncthreads per iter (its implicit
// vmcnt(0) drains the prefetch after ~350cyc of MFMA instead of immediately).
template<int EPI, int BM>
__global__ __launch_bounds__(256,2) void gemm_bt(
    const u16* __restrict__ A, const u16* __restrict__ Bt,
    int M, int N, int K,
    const float* __restrict__ bias,
    const float* __restrict__ gamma,
    const float* __restrict__ resid,
    float* __restrict__ outf,
    u16* __restrict__ outb0, u16* __restrict__ outb1)
{
  constexpr int MI = BM / 32;          // M fragments per wave
  __shared__ __align__(16) u16 at[2][BM*64];
  __shared__ __align__(16) u16 bt[2][128*64];
  int nwg = gridDim.x;
  int bidx = (blockIdx.x & 7) * (nwg >> 3) + (blockIdx.x >> 3);  // T1 XCD chunk
  int nb = N >> 7;
  int tm = bidx / nb, tn = bidx % nb;
  int m0 = tm * BM, n0 = tn << 7;
  int t = threadIdx.x, l = t & 63, w = t >> 6;
  int wr = (w >> 1) * (BM/2), wc = (w & 1) * 64;
  int fr = l & 15, fq = l >> 4;
  f32x4 acc[MI][4] = {};
  int rr = t >> 3;                // 0..31, staging row within 32-row round
  int cb = (t & 7) << 4;          // 0..112, staging 16B chunk
  const char* Ab = (const char*)A;
  const char* Bp = (const char*)Bt;
  long ld = (long)K * 2;

#define G_STAGE(s, kt) do {                                                        \
    _Pragma("unroll")                                                              \
    for (int c = 0; c < MI; c++) {                                                 \
      int row = c*32 + rr;                                                         \
      gload16(Ab + (long)(m0 + row)*ld + (long)(kt)*2 + (cb ^ ((row & 7) << 4)),   \
              (char*)at[s] + c*4096 + w*1024);                                     \
    }                                                                              \
    _Pragma("unroll")                                                              \
    for (int c = 0; c < 4; c++) {                                                  \
      int row = c*32 + rr;                                                         \
      gload16(Bp + (long)(n0 + row)*ld + (long)(kt)*2 + (cb ^ ((row & 7) << 4)),   \
              (char*)bt[s] + c*4096 + w*1024);                                     \
    }                                                                              \
  } while (0)

  G_STAGE(0, 0);
  __syncthreads();
  int cur = 0;
  for (int kt = 0; kt < K; kt += 64) {
    if (kt + 64 < K) G_STAGE(cur ^ 1, kt + 64);
    #pragma unroll
    for (int ka = 0; ka < 2; ka++) {
      bf16x8 af[MI], bfv[4];
      #pragma unroll
      for (int i = 0; i < MI; i++) {
        int ra = wr + i*16 + fr;
        af[i] = *(const bf16x8*)((const char*)at[cur] + ra*128 + ((ka*64 + fq*16) ^ ((ra & 7) << 4)));
      }
      #pragma unroll
      for (int j = 0; j < 4; j++) {
        int rb = wc + j*16 + fr;
        bfv[j] = *(const bf16x8*)((const char*)bt[cur] + rb*128 + ((ka*64 + fq*16) ^ ((rb & 7) << 4)));
      }
      #pragma unroll
      for (int i = 0; i < MI; i++)
        #pragma unroll
        for (int j = 0; j < 4; j++)
          acc[i][j] = MFMA16(af[i], bfv[j], acc[i][j]);
    }
    __syncthreads();      // implicit vmcnt(0): prefetch landed; buffers swap safe
    cur ^= 1;
  }
#undef G_STAGE
  #pragma unroll
  for (int i = 0; i < MI; i++) {
    #pragma unroll
    for (int j = 0; j < 4; j++) {
      #pragma unroll
      for (int r = 0; r < 4; r++) {
        int row = m0 + wr + i*16 + fq*4 + r;
        int col = n0 + wc + j*16 + fr;
        float v = acc[i][j][r];
        if constexpr (EPI == 0) {
          float qv = (v + bias[col]) * 0.18033688011112042f;  // (1/8)*log2(e)
          int b = row >> 10, lq = row & 1023, h = col >> 6, hd = col & 63;
          outb0[(((long)(b*16 + h)) << 16) + (lq << 6) + hd] = f2bf(qv);
        } else if constexpr (EPI == 1) {
          float u = v + bias[col];
          int b = row >> 11, p = row & 2047;
          if (col < 1024) {
            int h = col >> 6, hd = col & 63;
            outb0[(((long)((b*16 + h)*2048 + p)) << 6) + hd] = f2bf(u);
          } else {
            int c2 = col - 1024, h = c2 >> 6, hd = c2 & 63;
            outb1[(((long)((b*16 + h)*64 + hd)) << 11) + p] = f2bf(u);  // V^T
          }
        } else if constexpr (EPI == 2) {
          float gs = gamma[col]; gs = fminf(fmaxf(gs, -10.f), 10.f);
          long idx = (long)row*1024 + col;
          outf[idx] = resid[idx] + (v + bias[col]) * gs;
        } else if constexpr (EPI == 3) {
          float u = v + bias[col];
          float ge = 0.5f * u * (1.0f + erff(u * 0.70710678118654752f));
          outb0[(long)row*4096 + col] = f2bf(ge);
        } else {
          float gs = gamma[col]; gs = fminf(fmaxf(gs, -10.f), 10.f);
          long idx = (long)row*1024 + col;
          outf[idx] = resid[idx] + (v + bias[col]) * gs;
        }
      }
    }
  }
}

// ---------------- flash attention fwd: BARRIER-FREE, 1 wave per block --------
// block = 64 threads = 1 wave owning 16 q rows; KV tiles of 32; wave-private
// K double-buffer in LDS (global_load_lds needs no cross-wave sync); counted
// vmcnt(4) keeps next K tile in flight; no __syncthreads anywhere -> 15
// independent waves/CU hide each other's chain stalls.
__global__ __launch_bounds__(64, 4) void flash_fwd(
    const u16* __restrict__ q, const u16* __restrict__ k,
    const u16* __restrict__ vt, u16* __restrict__ ctx,
    float* __restrict__ ilout)
{
  __shared__ __align__(16) u16 ks[2][32*64];   // 8 KB dbuf K tile
  __shared__ __align__(16) char ps[2304];      // Q-stage then P (16 x stride 80)
  int nwg = gridDim.x;
  int bid = (blockIdx.x & 7) * (nwg >> 3) + (blockIdx.x >> 3);  // T1 XCD chunk
  int qt = bid & 63, h = (bid >> 6) & 15, b = bid >> 10;
  int q0 = qt << 4;
  int l = threadIdx.x & 63;
  int fr = l & 15, fq = l >> 4;
  const char* qb = (const char*)(q  + (((long)(b*16 + h)) << 16));
  const char* kb = (const char*)(k  + (((long)(b*16 + h)) << 17));
  const char* vb = (const char*)(vt + (((long)(b*16 + h)) << 17));
  int sr = l >> 3, sc = (l & 7) << 4;

  // prologue: stage K tile 0 + the 16 Q rows; single wave -> no barrier
  #pragma unroll
  for (int c = 0; c < 4; c++) {
    int row = c*8 + sr;
    gload16(kb + (long)row*128 + (sc ^ ((row & 7) << 4)), (char*)ks[0] + c*1024);
  }
  #pragma unroll
  for (int c = 0; c < 2; c++) {
    int row = c*8 + sr;
    gload16(qb + (long)(q0 + row)*128 + (sc ^ ((row & 7) << 4)), ps + c*1024);
  }
  asm volatile("s_waitcnt vmcnt(0)" ::: "memory");
  bf16x8 qf0 = *(const bf16x8*)(ps + fr*128 + ((fq*16) ^ ((fr & 7) << 4)));
  bf16x8 qf1 = *(const bf16x8*)(ps + fr*128 + ((64 + fq*16) ^ ((fr & 7) << 4)));
  asm volatile("s_waitcnt lgkmcnt(0)" ::: "memory");
  __builtin_amdgcn_sched_barrier(0);

  f32x4 cacc[4] = {};
  f32x4 lrun = {0.f, 0.f, 0.f, 0.f};
  int cur = 0;
  for (int kt = 0; kt < 2048; kt += 32) {
    // V(t): 4 x 16B gathers (L2); issued first so vmcnt(4) below drains them
    bf16x8 vf[4];
    #pragma unroll
    for (int cfd = 0; cfd < 4; cfd++)
      vf[cfd] = *(const bf16x8*)(vb + (long)(cfd*16 + fr)*4096 + (long)(kt + fq*8)*2);
    // K(t+1) prefetch into other buffer (wave-private, no sync needed)
    if (kt + 32 < 2048) {
      #pragma unroll
      for (int c = 0; c < 4; c++) {
        int row = c*8 + sr;
        gload16(kb + (long)(kt + 32 + row)*128 + (sc ^ ((row & 7) << 4)),
                (char*)ks[cur ^ 1] + c*1024);
      }
    }
    // in-order retire: drains K(t)+V(t), leaves the 4 K(t+1) gloads in flight
    asm volatile("s_waitcnt vmcnt(4)" ::: "memory");
    __builtin_amdgcn_sched_barrier(0);
    // QK(t) from LDS
    const char* ksb = (const char*)ks[cur];
    f32x4 sf[2];
    #pragma unroll
    for (int cf = 0; cf < 2; cf++) {
      int row = cf*16 + fr;
      bf16x8 kf0 = *(const bf16x8*)(ksb + row*128 + ((fq*16) ^ ((row & 7) << 4)));
      bf16x8 kf1 = *(const bf16x8*)(ksb + row*128 + ((64 + fq*16) ^ ((row & 7) << 4)));
      f32x4 a = {};
      a = MFMA16(qf0, kf0, a);
      sf[cf] = MFMA16(qf1, kf1, a);
    }
    // softmax (m==0, exp2; log2e folded into q-proj) + P write (stride 80)
    #pragma unroll
    for (int cf = 0; cf < 2; cf++)
      #pragma unroll
      for (int r = 0; r < 4; r++) {
        float pv = exp2f(sf[cf][r]);
        lrun[r] += pv;
        union { float f; unsigned int u; } pu; pu.f = pv;
        *(u16*)(ps + (fq*4 + r)*80 + ((cf*16 + fr) << 1)) = (u16)(pu.u >> 16);
      }
    bf16x8 pa = *(const bf16x8*)(ps + fr*80 + fq*16);
    #pragma unroll
    for (int cfd = 0; cfd < 4; cfd++)
      cacc[cfd] = MFMA16(pa, vf[cfd], cacc[cfd]);
    cur ^= 1;
  }
  float il4[4];
  #pragma unroll
  for (int r = 0; r < 4; r++) {
    float s = lrun[r];
    #pragma unroll
    for (int msk = 1; msk < 16; msk <<= 1) s += __shfl_xor(s, msk, 16);
    il4[r] = 1.0f / s;
  }
  #pragma unroll
  for (int cf = 0; cf < 4; cf++)
    #pragma unroll
    for (int r = 0; r < 4; r++) {
      int row = q0 + fq*4 + r;
      int col = h*64 + cf*16 + fr;
      ctx[(long)(b*1024 + row)*1024 + col] = f2bf(cacc[cf][r] * il4[r]);
    }
  if (fr == 0) {
    #pragma unroll
    for (int r = 0; r < 4; r++) {
      int row = q0 + fq*4 + r;
      long idx = (((long)(b*16 + h)) << 10) + row;
      ilout[idx] = il4[r];
    }
  }
}

// ---------------- attn mean over heads (GEMM-style, double-buffered) ---------
__global__ __launch_bounds__(256,2) void attn_mean(
    const u16* __restrict__ q, const u16* __restrict__ k,
    const float* __restrict__ il,
    float* __restrict__ out)
{
  __shared__ __align__(16) u16 qs[2][128*64];
  __shared__ __align__(16) u16 ks[2][128*64];
  __shared__ __align__(16) float ml[2][128];   // il for 128 q-rows
  int nwg = gridDim.x;
  int bid = (blockIdx.x & 7) * (nwg >> 3) + (blockIdx.x >> 3);  // T1 XCD chunk
  int kt = bid & 15, qt = (bid >> 4) & 7, b = bid >> 7;
  int q0 = qt << 7, k0 = kt << 7;
  int t = threadIdx.x, l = t & 63, w = t >> 6;
  int wr = (w >> 1) << 6, wc = (w & 1) << 6;
  int fr = l & 15, fq = l >> 4;
  int rr = t >> 3, cbb = (t & 7) << 4;
  const long bh = (long)b * 16;

#define AM_STAGE(hh, s) do {                                                        \
    const char* qb_ = (const char*)(q + ((bh + (hh)) << 16)) + (long)q0*128;        \
    const char* kb_ = (const char*)(k + ((bh + (hh)) << 17)) + (long)k0*128;        \
    _Pragma("unroll")                                                               \
    for (int c = 0; c < 4; c++) {                                                   \
      int row = c*32 + rr;                                                          \
      int sw = cbb ^ ((row & 7) << 4);                                              \
      gload16(qb_ + (long)row*128 + sw, (char*)qs[s] + c*4096 + w*1024);            \
      gload16(kb_ + (long)row*128 + sw, (char*)ks[s] + c*4096 + w*1024);            \
    }                                                                               \
    if (w == 0 && l < 32) {                                                         \
      gload16((const char*)(il + ((bh + (hh)) << 10) + q0) + l*16, (char*)ml[s]);   \
    }                                                                               \
  } while (0)

  AM_STAGE(0, 0);
  asm volatile("s_waitcnt vmcnt(0)" ::: "memory");
  __builtin_amdgcn_s_barrier();
  asm volatile("" ::: "memory");

  f32x4 macc[4][4] = {};
  for (int h = 0; h < 16; h++) {
    int cur = h & 1;
    if (h < 15) AM_STAGE(h + 1, cur ^ 1);
    const char* qsb = (const char*)qs[cur];
    const char* ksb = (const char*)ks[cur];
    const float* mlb = ml[cur];
    f32x4 ir4[4];
    #pragma unroll
    for (int i = 0; i < 4; i++)
      ir4[i] = *(const f32x4*)(mlb + wr + i*16 + fq*4);
    bf16x8 af[4][2], bf[4][2];
    #pragma unroll
    for (int i = 0; i < 4; i++) {
      int ra = wr + i*16 + fr;
      int rb = wc + i*16 + fr;
      af[i][0] = *(const bf16x8*)(qsb + ra*128 + ((fq*16) ^ ((ra & 7) << 4)));
      af[i][1] = *(const bf16x8*)(qsb + ra*128 + ((64 + fq*16) ^ ((ra & 7) << 4)));
      bf[i][0] = *(const bf16x8*)(ksb + rb*128 + ((fq*16) ^ ((rb & 7) << 4)));
      bf[i][1] = *(const bf16x8*)(ksb + rb*128 + ((64 + fq*16) ^ ((rb & 7) << 4)));
    }
    #pragma unroll
    for (int j = 0; j < 4; j++) {
      f32x4 sf[4];
      __builtin_amdgcn_s_setprio(1);
      #pragma unroll
      for (int i = 0; i < 4; i++) {
        f32x4 a = MFMA16(af[i][0], bf[j][0], {});
        sf[i] = MFMA16(af[i][1], bf[j][1], a);
      }
      __builtin_amdgcn_s_setprio(0);
      #pragma unroll
      for (int i = 0; i < 4; i++)
        #pragma unroll
        for (int r = 0; r < 4; r++)
          macc[i][j][r] += exp2f(sf[i][r]) * ir4[i][r];
    }
    asm volatile("s_waitcnt vmcnt(0)" ::: "memory");
    __builtin_amdgcn_s_barrier();
    asm volatile("" ::: "memory");
  }
#undef AM_STAGE
  #pragma unroll
  for (int i = 0; i < 4; i++)
    #pragma unroll
    for (int j = 0; j < 4; j++)
      #pragma unroll
      for (int r = 0; r < 4; r++) {
        int row = q0 + wr + i*16 + fq*4 + r;
        int col = k0 + wc + j*16 + fr;
        out[((long)(b*1024 + row) << 11) + col] = macc[i][j][r] * 0.0625f;
      }
}

extern "C" void kernel_launch(void* const* d_in, const int* in_sizes, int n_in,
                              void* d_out, int out_size, void* d_ws, size_t ws_size,
                              hipStream_t stream)
{
  (void)in_sizes; (void)n_in; (void)out_size; (void)ws_size;
  const float* tight = (const float*)d_in[0];
  const float* ctxt  = (const float*)d_in[1];
  const float* nbh   = (const float*)d_in[2];
  const float* lnqg  = (const float*)d_in[3];
  const float* lnqb  = (const float*)d_in[4];
  const float* lnkg  = (const float*)d_in[5];
  const float* lnkb  = (const float*)d_in[6];
  const float* wqkv  = (const float*)d_in[7];
  const float* bqkv  = (const float*)d_in[8];
  const float* wo    = (const float*)d_in[9];
  const float* bo    = (const float*)d_in[10];
  const float* cg    = (const float*)d_in[11];
  const float* lnfg  = (const float*)d_in[12];
  const float* lnfb  = (const float*)d_in[13];
  const float* w1    = (const float*)d_in[14];
  const float* b1    = (const float*)d_in[15];
  const float* w2    = (const float*)d_in[16];
  const float* b2    = (const float*)d_in[17];
  const float* fg    = (const float*)d_in[18];

  char* p = (char*)d_ws;
  u16* wqkv_bf = (u16*)p; p += 3072L*1024*2;
  u16* wo_bf   = (u16*)p; p += 1024L*1024*2;
  u16* w1_bf   = (u16*)p; p += 4096L*1024*2;
  u16* w2_bf   = (u16*)p; p += 1024L*4096*2;
  u16* qin_bf  = (u16*)p; p += 4096L*1024*2;
  u16* kvin_bf = (u16*)p; p += 8192L*1024*2;
  u16* q_bf    = (u16*)p; p += 4L*16*1024*64*2;
  u16* k_bf    = (u16*)p; p += 4L*16*2048*64*2;
  u16* vt_bf   = (u16*)p; p += 4L*16*64*2048*2;
  u16* ctx_bf  = (u16*)p; p += 4096L*1024*2;
  float* il_f  = (float*)p; p += 4L*16*1024*4;
  float* x_f   = (float*)p; p += 4096L*1024*4;
  u16* hln_bf  = (u16*)p; p += 4096L*1024*2;
  u16* gelu_bf = (u16*)p; p += 4096L*4096*2;

  float* x_out    = (float*)d_out;           // [4,1024,1024]
  float* mean_out = x_out + 4194304;         // [4,1024,2048]

  cvt_weights<<<12288, 256, 0, stream>>>(wqkv, wo, w1, w2, wqkv_bf, wo_bf, w1_bf, w2_bf);
  ln_kernel<0><<<4096, 256, 0, stream>>>(tight, nullptr, lnqg, lnqb, qin_bf);
  ln_kernel<1><<<8192, 256, 0, stream>>>(ctxt, nbh, lnkg, lnkb, kvin_bf);
  gemm_bt<0,64><<<512, 256, 0, stream>>>(qin_bf, wqkv_bf, 4096, 1024, 1024,
                                      bqkv, nullptr, nullptr, nullptr, q_bf, nullptr);
  gemm_bt<1,128><<<1024, 256, 0, stream>>>(kvin_bf, wqkv_bf + 1024L*1024, 8192, 2048, 1024,
                                       bqkv + 1024, nullptr, nullptr, nullptr, k_bf, vt_bf);
  flash_fwd<<<4096, 64, 0, stream>>>(q_bf, k_bf, vt_bf, ctx_bf, il_f);
  attn_mean<<<512, 256, 0, stream>>>(q_bf, k_bf, il_f, mean_out);
  gemm_bt<2,64><<<512, 256, 0, stream>>>(ctx_bf, wo_bf, 4096, 1024, 1024,
                                      bo, cg, tight, x_f, nullptr, nullptr);
  ln_kernel<0><<<4096, 256, 0, stream>>>(x_f, nullptr, lnfg, lnfb, hln_bf);
  gemm_bt<3,128><<<1024, 256, 0, stream>>>(hln_bf, w1_bf, 4096, 4096, 1024,
                                       b1, nullptr, nullptr, nullptr, gelu_bf, nullptr);
  gemm_bt<4,64><<<512, 256, 0, stream>>>(gelu_bf, w2_bf, 4096, 1024, 4096,
                                      b2, fg, x_f, x_out, nullptr, nullptr);
}

// Round 9
// 376.967 us; speedup vs baseline: 1.2581x; 1.2581x over previous
//
#include <hip/hip_runtime.h>
#include <math.h>

typedef unsigned short u16;
typedef __attribute__((ext_vector_type(8))) short bf16x8;
typedef __attribute__((ext_vector_type(4))) float f32x4;

#define MFMA16(a,b,c) __builtin_amdgcn_mfma_f32_16x16x32_bf16(a,b,c,0,0,0)

__device__ __forceinline__ u16 f2bf(float f){
  union { float f; unsigned int u; } x; x.f = f;
  unsigned int r = x.u + 0x7fffu + ((x.u >> 16) & 1u);
  return (u16)(r >> 16);
}

__device__ __forceinline__ void gload16(const void* g, void* lds){
  __builtin_amdgcn_global_load_lds(
    (const __attribute__((address_space(1))) unsigned int*)g,
    (__attribute__((address_space(3))) unsigned int*)lds, 16, 0, 0);
}

// ---------------- weights fp32 -> bf16 ---------------------------------------
__global__ __launch_bounds__(256) void cvt_weights(
    const float* __restrict__ wqkv, const float* __restrict__ wo,
    const float* __restrict__ w1, const float* __restrict__ w2,
    u16* __restrict__ o0, u16* __restrict__ o1,
    u16* __restrict__ o2, u16* __restrict__ o3)
{
  int idx = blockIdx.x * 256 + threadIdx.x;   // quad index, 3145728 total
  const float* src; u16* dst;
  if (idx < 786432)                    { src = wqkv; dst = o0; }
  else if ((idx -= 786432) < 262144)   { src = wo;   dst = o1; }
  else if ((idx -= 262144) < 1048576)  { src = w1;   dst = o2; }
  else { idx -= 1048576;                 src = w2;   dst = o3; }
  float4 v = ((const float4*)src)[idx];
  short4 o;
  o.x = (short)f2bf(v.x); o.y = (short)f2bf(v.y);
  o.z = (short)f2bf(v.z); o.w = (short)f2bf(v.w);
  ((short4*)dst)[idx] = o;
}

// ---------------- layernorm over D=1024, out bf16 ----------------------------
template<int MODE>
__global__ __launch_bounds__(256) void ln_kernel(
    const float* __restrict__ s0, const float* __restrict__ s1,
    const float* __restrict__ g, const float* __restrict__ be,
    u16* __restrict__ out)
{
  int row = blockIdx.x, t = threadIdx.x;
  const float* src;
  if (MODE == 1) {
    int b = row >> 11, p = row & 2047;
    src = (p < 1024) ? s0 + ((long)(b*1024 + p))*1024
                     : s1 + ((long)(b*1024 + p - 1024))*1024;
  } else {
    src = s0 + (long)row * 1024;
  }
  float4 v = ((const float4*)src)[t];
  float s  = v.x + v.y + v.z + v.w;
  float ss = v.x*v.x + v.y*v.y + v.z*v.z + v.w*v.w;
  #pragma unroll
  for (int m = 1; m < 64; m <<= 1) { s += __shfl_xor(s, m); ss += __shfl_xor(ss, m); }
  __shared__ float red[8];
  int l = t & 63, w = t >> 6;
  if (l == 0) { red[w*2] = s; red[w*2+1] = ss; }
  __syncthreads();
  s  = red[0] + red[2] + red[4] + red[6];
  ss = red[1] + red[3] + red[5] + red[7];
  float mean = s * (1.0f/1024.0f);
  float var  = ss * (1.0f/1024.0f) - mean*mean;
  float rstd = rsqrtf(var + 1e-5f);
  float4 gv = ((const float4*)g)[t];
  float4 bv = ((const float4*)be)[t];
  short4 o;
  o.x = (short)f2bf((v.x-mean)*rstd*gv.x + bv.x);
  o.y = (short)f2bf((v.y-mean)*rstd*gv.y + bv.y);
  o.z = (short)f2bf((v.z-mean)*rstd*gv.z + bv.z);
  o.w = (short)f2bf((v.w-mean)*rstd*gv.w + bv.w);
  *(short4*)(out + (long)row*1024 + t*4) = o;
}

// ---------------- bf16 GEMM, C = A[M,K] * Bt[N,K]^T, BK=64 -------------------
// (round-7 version, unchanged: part of the known-437 config)
template<int EPI, int BM>
__global__ __launch_bounds__(256,2) void gemm_bt(
    const u16* __restrict__ A, const u16* __restrict__ Bt,
    int M, int N, int K,
    const float* __restrict__ bias,
    const float* __restrict__ gamma,
    const float* __restrict__ resid,
    float* __restrict__ outf,
    u16* __restrict__ outb0, u16* __restrict__ outb1)
{
  constexpr int MI = BM / 32;          // M fragments per wave
  __shared__ __align__(16) u16 at[BM*64];
  __shared__ __align__(16) u16 bt[128*64];
  int nwg = gridDim.x;
  int bidx = (blockIdx.x & 7) * (nwg >> 3) + (blockIdx.x >> 3);  // T1 XCD chunk
  int nb = N >> 7;
  int tm = bidx / nb, tn = bidx % nb;
  int m0 = tm * BM, n0 = tn << 7;
  int t = threadIdx.x, l = t & 63, w = t >> 6;
  int wr = (w >> 1) * (BM/2), wc = (w & 1) * 64;
  int fr = l & 15, fq = l >> 4;
  f32x4 acc[MI][4] = {};
  int rr = t >> 3;                // 0..31, staging row within 32-row round
  int cb = (t & 7) << 4;          // 0..112, staging 16B chunk
  const char* Ab = (const char*)A;
  const char* Bp = (const char*)Bt;
  long ld = (long)K * 2;
  for (int kt = 0; kt < K; kt += 64) {
    #pragma unroll
    for (int c = 0; c < MI; c++) {
      int row = c*32 + rr;
      gload16(Ab + (long)(m0 + row)*ld + (long)kt*2 + (cb ^ ((row & 7) << 4)),
              (char*)at + c*4096 + w*1024);
    }
    #pragma unroll
    for (int c = 0; c < 4; c++) {
      int row = c*32 + rr;
      gload16(Bp + (long)(n0 + row)*ld + (long)kt*2 + (cb ^ ((row & 7) << 4)),
              (char*)bt + c*4096 + w*1024);
    }
    __syncthreads();
    #pragma unroll
    for (int ka = 0; ka < 2; ka++) {
      bf16x8 af[MI], bfv[4];
      #pragma unroll
      for (int i = 0; i < MI; i++) {
        int ra = wr + i*16 + fr;
        af[i] = *(const bf16x8*)((const char*)at + ra*128 + ((ka*64 + fq*16) ^ ((ra & 7) << 4)));
      }
      #pragma unroll
      for (int j = 0; j < 4; j++) {
        int rb = wc + j*16 + fr;
        bfv[j] = *(const bf16x8*)((const char*)bt + rb*128 + ((ka*64 + fq*16) ^ ((rb & 7) << 4)));
      }
      #pragma unroll
      for (int i = 0; i < MI; i++)
        #pragma unroll
        for (int j = 0; j < 4; j++)
          acc[i][j] = MFMA16(af[i], bfv[j], acc[i][j]);
    }
    __syncthreads();
  }
  #pragma unroll
  for (int i = 0; i < MI; i++) {
    #pragma unroll
    for (int j = 0; j < 4; j++) {
      #pragma unroll
      for (int r = 0; r < 4; r++) {
        int row = m0 + wr + i*16 + fq*4 + r;
        int col = n0 + wc + j*16 + fr;
        float v = acc[i][j][r];
        if constexpr (EPI == 0) {
          float qv = (v + bias[col]) * 0.18033688011112042f;  // (1/8)*log2(e)
          int b = row >> 10, lq = row & 1023, h = col >> 6, hd = col & 63;
          outb0[(((long)(b*16 + h)) << 16) + (lq << 6) + hd] = f2bf(qv);
        } else if constexpr (EPI == 1) {
          float u = v + bias[col];
          int b = row >> 11, p = row & 2047;
          if (col < 1024) {
            int h = col >> 6, hd = col & 63;
            outb0[(((long)((b*16 + h)*2048 + p)) << 6) + hd] = f2bf(u);
          } else {
            int c2 = col - 1024, h = c2 >> 6, hd = c2 & 63;
            outb1[(((long)((b*16 + h)*64 + hd)) << 11) + p] = f2bf(u);  // V^T
          }
        } else if constexpr (EPI == 2) {
          float gs = gamma[col]; gs = fminf(fmaxf(gs, -10.f), 10.f);
          long idx = (long)row*1024 + col;
          outf[idx] = resid[idx] + (v + bias[col]) * gs;
        } else if constexpr (EPI == 3) {
          float u = v + bias[col];
          float ge = 0.5f * u * (1.0f + erff(u * 0.70710678118654752f));
          outb0[(long)row*4096 + col] = f2bf(ge);
        } else {
          float gs = gamma[col]; gs = fminf(fmaxf(gs, -10.f), 10.f);
          long idx = (long)row*1024 + col;
          outf[idx] = resid[idx] + (v + bias[col]) * gs;
        }
      }
    }
  }
}

// ---------------- flash attention fwd (V staged in LDS once per block) -------
// block = (b, h, 64 q-rows); 4 waves x 16 rows; KV tiles of 64.
// Per iter: issue V-stage(t) [first] + K-prefetch(t+1) [second] -> QK(t) from
// ks[cur] -> softmax + P-write -> vmcnt(2) [V landed, K still in flight] +
// barrier -> PV from V-LDS (swizzled b128, conflict-minimal) -> vmcnt(0) +
// barrier [K landed, vs reads done]. V global traffic: 8KB/block/iter
// (was 32KB: every wave gathered the full tile at 4KB lane stride).
__global__ __launch_bounds__(256, 4) void flash_fwd(
    const u16* __restrict__ q, const u16* __restrict__ k,
    const u16* __restrict__ vt, u16* __restrict__ ctx,
    float* __restrict__ ilout)
{
  __shared__ __align__(16) u16 ks[2][64*64];   // 16 KB dbuf K tile
  __shared__ __align__(16) u16 vs[64*64];      // 8 KB V tile [hd][64kv]
  __shared__ __align__(16) char ps[4*2304];    // per-wave Q-stage then P (16x144B)
  int nwg = gridDim.x;
  int bid = (blockIdx.x & 7) * (nwg >> 3) + (blockIdx.x >> 3);  // T1 XCD chunk
  int qt = bid & 15, h = (bid >> 4) & 15, b = bid >> 8;
  int q0 = qt << 6;
  int t = threadIdx.x, l = t & 63, w = t >> 6;
  int fr = l & 15, fq = l >> 4;
  const char* qb = (const char*)(q  + (((long)(b*16 + h)) << 16));
  const char* kb = (const char*)(k  + (((long)(b*16 + h)) << 17));
  const char* vb = (const char*)(vt + (((long)(b*16 + h)) << 17));
  char* psw = ps + w*2304;
  int rr = t >> 3;                // 0..31 block staging row
  int sc = (t & 7) << 4;          // 16B chunk within 128B row

  // prologue: stage K tile 0 + this wave's 16 Q rows
  #pragma unroll
  for (int c = 0; c < 2; c++) {
    int row = c*32 + rr;
    gload16(kb + (long)row*128 + (sc ^ ((row & 7) << 4)), (char*)ks[0] + c*4096 + w*1024);
  }
  {
    int qr = l >> 3;
    #pragma unroll
    for (int c = 0; c < 2; c++) {
      int row = c*8 + qr;
      gload16(qb + (long)(q0 + w*16 + row)*128 + (sc ^ ((row & 7) << 4)), psw + c*1024);
    }
  }
  asm volatile("s_waitcnt vmcnt(0)" ::: "memory");
  bf16x8 qf0 = *(const bf16x8*)(psw + fr*128 + ((fq*16) ^ ((fr & 7) << 4)));
  bf16x8 qf1 = *(const bf16x8*)(psw + fr*128 + ((64 + fq*16) ^ ((fr & 7) << 4)));
  asm volatile("s_waitcnt lgkmcnt(0)" ::: "memory");
  __builtin_amdgcn_s_barrier();
  asm volatile("" ::: "memory");

  f32x4 cacc[4] = {};
  f32x4 lrun = {0.f, 0.f, 0.f, 0.f};
  int cur = 0;
  for (int kt = 0; kt < 2048; kt += 64) {
    int notlast = (kt + 64 < 2048);
    // V-stage(t) FIRST (2 gloads/thread): [hd 64][kv 64], coalesced rows,
    // source pre-swizzled so linear-dest LDS holds swizzled layout (rule 21)
    #pragma unroll
    for (int c = 0; c < 2; c++) {
      int hd = c*32 + rr;
      gload16(vb + (long)hd*4096 + (long)kt*2 + (sc ^ ((hd & 7) << 4)),
              (char*)vs + c*4096 + w*1024);
    }
    // K-prefetch(t+1) SECOND (2 gloads/thread)
    if (notlast) {
      #pragma unroll
      for (int c = 0; c < 2; c++) {
        int row = c*32 + rr;
        gload16(kb + (long)(kt + 64 + row)*128 + (sc ^ ((row & 7) << 4)),
                (char*)ks[cur ^ 1] + c*4096 + w*1024);
      }
    }
    __builtin_amdgcn_sched_barrier(0);
    // QK(t) from ks[cur]
    const char* ksb = (const char*)ks[cur];
    f32x4 sf[4];
    __builtin_amdgcn_s_setprio(1);
    #pragma unroll
    for (int cf = 0; cf < 4; cf++) {
      int row = cf*16 + fr;
      bf16x8 kf0 = *(const bf16x8*)(ksb + row*128 + ((fq*16) ^ ((row & 7) << 4)));
      bf16x8 kf1 = *(const bf16x8*)(ksb + row*128 + ((64 + fq*16) ^ ((row & 7) << 4)));
      f32x4 a = {};
      a = MFMA16(qf0, kf0, a);
      sf[cf] = MFMA16(qf1, kf1, a);
    }
    __builtin_amdgcn_s_setprio(0);
    // softmax (m==0; log2e folded into q-proj) + P write (per-wave, stride 144)
    #pragma unroll
    for (int cf = 0; cf < 4; cf++)
      #pragma unroll
      for (int r = 0; r < 4; r++) {
        float pv = exp2f(sf[cf][r]);
        lrun[r] += pv;
        union { float f; unsigned int u; } pu; pu.f = pv;
        *(u16*)(psw + (fq*4 + r)*144 + ((cf*16 + fr) << 1)) = (u16)(pu.u >> 16);
      }
    // V landed? (own 2 V gloads retired; K's 2 still in flight)
    if (notlast) { asm volatile("s_waitcnt vmcnt(2)" ::: "memory"); }
    else         { asm volatile("s_waitcnt vmcnt(0)" ::: "memory"); }
    __builtin_amdgcn_s_barrier();
    asm volatile("" ::: "memory");
    // PV from V-LDS (swizzled b128 reads) ; P fragments from psw
    bf16x8 pa0 = *(const bf16x8*)(psw + fr*144 + fq*16);
    bf16x8 pa1 = *(const bf16x8*)(psw + fr*144 + 64 + fq*16);
    __builtin_amdgcn_s_setprio(1);
    #pragma unroll
    for (int cfd = 0; cfd < 4; cfd++) {
      int hd = cfd*16 + fr;
      bf16x8 vf0 = *(const bf16x8*)((const char*)vs + hd*128 + ((fq*16) ^ ((hd & 7) << 4)));
      bf16x8 vf1 = *(const bf16x8*)((const char*)vs + hd*128 + ((64 + fq*16) ^ ((hd & 7) << 4)));
      cacc[cfd] = MFMA16(pa0, vf0, cacc[cfd]);
      cacc[cfd] = MFMA16(pa1, vf1, cacc[cfd]);
    }
    __builtin_amdgcn_s_setprio(0);
    if (notlast) {
      // K prefetch landed (had a full compute phase); all vs reads complete
      asm volatile("s_waitcnt vmcnt(0)" ::: "memory");
      __builtin_amdgcn_s_barrier();
      asm volatile("" ::: "memory");
    }
    cur ^= 1;
  }
  float il4[4];
  #pragma unroll
  for (int r = 0; r < 4; r++) {
    float s = lrun[r];
    #pragma unroll
    for (int msk = 1; msk < 16; msk <<= 1) s += __shfl_xor(s, msk, 16);
    il4[r] = 1.0f / s;
  }
  #pragma unroll
  for (int cf = 0; cf < 4; cf++)
    #pragma unroll
    for (int r = 0; r < 4; r++) {
      int row = q0 + w*16 + fq*4 + r;
      int col = h*64 + cf*16 + fr;
      ctx[(long)(b*1024 + row)*1024 + col] = f2bf(cacc[cf][r] * il4[r]);
    }
  if (fr == 0) {
    #pragma unroll
    for (int r = 0; r < 4; r++) {
      int row = q0 + w*16 + fq*4 + r;
      long idx = (((long)(b*16 + h)) << 10) + row;
      ilout[idx] = il4[r];
    }
  }
}

// ---------------- attn mean over heads (GEMM-style, double-buffered) ---------
__global__ __launch_bounds__(256,2) void attn_mean(
    const u16* __restrict__ q, const u16* __restrict__ k,
    const float* __restrict__ il,
    float* __restrict__ out)
{
  __shared__ __align__(16) u16 qs[2][128*64];
  __shared__ __align__(16) u16 ks[2][128*64];
  __shared__ __align__(16) float ml[2][128];   // il for 128 q-rows
  int nwg = gridDim.x;
  int bid = (blockIdx.x & 7) * (nwg >> 3) + (blockIdx.x >> 3);  // T1 XCD chunk
  int kt = bid & 15, qt = (bid >> 4) & 7, b = bid >> 7;
  int q0 = qt << 7, k0 = kt << 7;
  int t = threadIdx.x, l = t & 63, w = t >> 6;
  int wr = (w >> 1) << 6, wc = (w & 1) << 6;
  int fr = l & 15, fq = l >> 4;
  int rr = t >> 3, cbb = (t & 7) << 4;
  const long bh = (long)b * 16;

#define AM_STAGE(hh, s) do {                                                        \
    const char* qb_ = (const char*)(q + ((bh + (hh)) << 16)) + (long)q0*128;        \
    const char* kb_ = (const char*)(k + ((bh + (hh)) << 17)) + (long)k0*128;        \
    _Pragma("unroll")                                                               \
    for (int c = 0; c < 4; c++) {                                                   \
      int row = c*32 + rr;                                                          \
      int sw = cbb ^ ((row & 7) << 4);                                              \
      gload16(qb_ + (long)row*128 + sw, (char*)qs[s] + c*4096 + w*1024);            \
      gload16(kb_ + (long)row*128 + sw, (char*)ks[s] + c*4096 + w*1024);            \
    }                                                                               \
    if (w == 0 && l < 32) {                                                         \
      gload16((const char*)(il + ((bh + (hh)) << 10) + q0) + l*16, (char*)ml[s]);   \
    }                                                                               \
  } while (0)

  AM_STAGE(0, 0);
  asm volatile("s_waitcnt vmcnt(0)" ::: "memory");
  __builtin_amdgcn_s_barrier();
  asm volatile("" ::: "memory");

  f32x4 macc[4][4] = {};
  for (int h = 0; h < 16; h++) {
    int cur = h & 1;
    if (h < 15) AM_STAGE(h + 1, cur ^ 1);
    const char* qsb = (const char*)qs[cur];
    const char* ksb = (const char*)ks[cur];
    const float* mlb = ml[cur];
    f32x4 ir4[4];
    #pragma unroll
    for (int i = 0; i < 4; i++)
      ir4[i] = *(const f32x4*)(mlb + wr + i*16 + fq*4);
    bf16x8 af[4][2], bf[4][2];
    #pragma unroll
    for (int i = 0; i < 4; i++) {
      int ra = wr + i*16 + fr;
      int rb = wc + i*16 + fr;
      af[i][0] = *(const bf16x8*)(qsb + ra*128 + ((fq*16) ^ ((ra & 7) << 4)));
      af[i][1] = *(const bf16x8*)(qsb + ra*128 + ((64 + fq*16) ^ ((ra & 7) << 4)));
      bf[i][0] = *(const bf16x8*)(ksb + rb*128 + ((fq*16) ^ ((rb & 7) << 4)));
      bf[i][1] = *(const bf16x8*)(ksb + rb*128 + ((64 + fq*16) ^ ((rb & 7) << 4)));
    }
    #pragma unroll
    for (int j = 0; j < 4; j++) {
      f32x4 sf[4];
      __builtin_amdgcn_s_setprio(1);
      #pragma unroll
      for (int i = 0; i < 4; i++) {
        f32x4 a = MFMA16(af[i][0], bf[j][0], {});
        sf[i] = MFMA16(af[i][1], bf[j][1], a);
      }
      __builtin_amdgcn_s_setprio(0);
      #pragma unroll
      for (int i = 0; i < 4; i++)
        #pragma unroll
        for (int r = 0; r < 4; r++)
          macc[i][j][r] += exp2f(sf[i][r]) * ir4[i][r];
    }
    asm volatile("s_waitcnt vmcnt(0)" ::: "memory");
    __builtin_amdgcn_s_barrier();
    asm volatile("" ::: "memory");
  }
#undef AM_STAGE
  #pragma unroll
  for (int i = 0; i < 4; i++)
    #pragma unroll
    for (int j = 0; j < 4; j++)
      #pragma unroll
      for (int r = 0; r < 4; r++) {
        int row = q0 + wr + i*16 + fq*4 + r;
        int col = k0 + wc + j*16 + fr;
        out[((long)(b*1024 + row) << 11) + col] = macc[i][j][r] * 0.0625f;
      }
}

extern "C" void kernel_launch(void* const* d_in, const int* in_sizes, int n_in,
                              void* d_out, int out_size, void* d_ws, size_t ws_size,
                              hipStream_t stream)
{
  (void)in_sizes; (void)n_in; (void)out_size; (void)ws_size;
  const float* tight = (const float*)d_in[0];
  const float* ctxt  = (const float*)d_in[1];
  const float* nbh   = (const float*)d_in[2];
  const float* lnqg  = (const float*)d_in[3];
  const float* lnqb  = (const float*)d_in[4];
  const float* lnkg  = (const float*)d_in[5];
  const float* lnkb  = (const float*)d_in[6];
  const float* wqkv  = (const float*)d_in[7];
  const float* bqkv  = (const float*)d_in[8];
  const float* wo    = (const float*)d_in[9];
  const float* bo    = (const float*)d_in[10];
  const float* cg    = (const float*)d_in[11];
  const float* lnfg  = (const float*)d_in[12];
  const float* lnfb  = (const float*)d_in[13];
  const float* w1    = (const float*)d_in[14];
  const float* b1    = (const float*)d_in[15];
  const float* w2    = (const float*)d_in[16];
  const float* b2    = (const float*)d_in[17];
  const float* fg    = (const float*)d_in[18];

  char* p = (char*)d_ws;
  u16* wqkv_bf = (u16*)p; p += 3072L*1024*2;
  u16* wo_bf   = (u16*)p; p += 1024L*1024*2;
  u16* w1_bf   = (u16*)p; p += 4096L*1024*2;
  u16* w2_bf   = (u16*)p; p += 1024L*4096*2;
  u16* qin_bf  = (u16*)p; p += 4096L*1024*2;
  u16* kvin_bf = (u16*)p; p += 8192L*1024*2;
  u16* q_bf    = (u16*)p; p += 4L*16*1024*64*2;
  u16* k_bf    = (u16*)p; p += 4L*16*2048*64*2;
  u16* vt_bf   = (u16*)p; p += 4L*16*64*2048*2;
  u16* ctx_bf  = (u16*)p; p += 4096L*1024*2;
  float* il_f  = (float*)p; p += 4L*16*1024*4;
  float* x_f   = (float*)p; p += 4096L*1024*4;
  u16* hln_bf  = (u16*)p; p += 4096L*1024*2;
  u16* gelu_bf = (u16*)p; p += 4096L*4096*2;

  float* x_out    = (float*)d_out;           // [4,1024,1024]
  float* mean_out = x_out + 4194304;         // [4,1024,2048]

  cvt_weights<<<12288, 256, 0, stream>>>(wqkv, wo, w1, w2, wqkv_bf, wo_bf, w1_bf, w2_bf);
  ln_kernel<0><<<4096, 256, 0, stream>>>(tight, nullptr, lnqg, lnqb, qin_bf);
  ln_kernel<1><<<8192, 256, 0, stream>>>(ctxt, nbh, lnkg, lnkb, kvin_bf);
  gemm_bt<0,64><<<512, 256, 0, stream>>>(qin_bf, wqkv_bf, 4096, 1024, 1024,
                                      bqkv, nullptr, nullptr, nullptr, q_bf, nullptr);
  gemm_bt<1,128><<<1024, 256, 0, stream>>>(kvin_bf, wqkv_bf + 1024L*1024, 8192, 2048, 1024,
                                       bqkv + 1024, nullptr, nullptr, nullptr, k_bf, vt_bf);
  flash_fwd<<<1024, 256, 0, stream>>>(q_bf, k_bf, vt_bf, ctx_bf, il_f);
  attn_mean<<<512, 256, 0, stream>>>(q_bf, k_bf, il_f, mean_out);
  gemm_bt<2,64><<<512, 256, 0, stream>>>(ctx_bf, wo_bf, 4096, 1024, 1024,
                                      bo, cg, tight, x_f, nullptr, nullptr);
  ln_kernel<0><<<4096, 256, 0, stream>>>(x_f, nullptr, lnfg, lnfb, hln_bf);
  gemm_bt<3,128><<<1024, 256, 0, stream>>>(hln_bf, w1_bf, 4096, 4096, 1024,
                                       b1, nullptr, nullptr, nullptr, gelu_bf, nullptr);
  gemm_bt<4,64><<<512, 256, 0, stream>>>(gelu_bf, w2_bf, 4096, 1024, 4096,
                                      b2, fg, x_f, x_out, nullptr, nullptr);
}

// Round 10
// 375.000 us; speedup vs baseline: 1.2647x; 1.0052x over previous
//
#include <hip/hip_runtime.h>
#include <math.h>

typedef unsigned short u16;
typedef __attribute__((ext_vector_type(8))) short bf16x8;
typedef __attribute__((ext_vector_type(4))) float f32x4;

#define MFMA16(a,b,c) __builtin_amdgcn_mfma_f32_16x16x32_bf16(a,b,c,0,0,0)

__device__ __forceinline__ u16 f2bf(float f){
  union { float f; unsigned int u; } x; x.f = f;
  unsigned int r = x.u + 0x7fffu + ((x.u >> 16) & 1u);
  return (u16)(r >> 16);
}

__device__ __forceinline__ void gload16(const void* g, void* lds){
  __builtin_amdgcn_global_load_lds(
    (const __attribute__((address_space(1))) unsigned int*)g,
    (__attribute__((address_space(3))) unsigned int*)lds, 16, 0, 0);
}

// ---------------- weights fp32 -> bf16 ---------------------------------------
__global__ __launch_bounds__(256) void cvt_weights(
    const float* __restrict__ wqkv, const float* __restrict__ wo,
    const float* __restrict__ w1, const float* __restrict__ w2,
    u16* __restrict__ o0, u16* __restrict__ o1,
    u16* __restrict__ o2, u16* __restrict__ o3)
{
  int idx = blockIdx.x * 256 + threadIdx.x;   // quad index, 3145728 total
  const float* src; u16* dst;
  if (idx < 786432)                    { src = wqkv; dst = o0; }
  else if ((idx -= 786432) < 262144)   { src = wo;   dst = o1; }
  else if ((idx -= 262144) < 1048576)  { src = w1;   dst = o2; }
  else { idx -= 1048576;                 src = w2;   dst = o3; }
  float4 v = ((const float4*)src)[idx];
  short4 o;
  o.x = (short)f2bf(v.x); o.y = (short)f2bf(v.y);
  o.z = (short)f2bf(v.z); o.w = (short)f2bf(v.w);
  ((short4*)dst)[idx] = o;
}

// ---------------- layernorm over D=1024, out bf16 ----------------------------
template<int MODE>
__global__ __launch_bounds__(256) void ln_kernel(
    const float* __restrict__ s0, const float* __restrict__ s1,
    const float* __restrict__ g, const float* __restrict__ be,
    u16* __restrict__ out)
{
  int row = blockIdx.x, t = threadIdx.x;
  const float* src;
  if (MODE == 1) {
    int b = row >> 11, p = row & 2047;
    src = (p < 1024) ? s0 + ((long)(b*1024 + p))*1024
                     : s1 + ((long)(b*1024 + p - 1024))*1024;
  } else {
    src = s0 + (long)row * 1024;
  }
  float4 v = ((const float4*)src)[t];
  float s  = v.x + v.y + v.z + v.w;
  float ss = v.x*v.x + v.y*v.y + v.z*v.z + v.w*v.w;
  #pragma unroll
  for (int m = 1; m < 64; m <<= 1) { s += __shfl_xor(s, m); ss += __shfl_xor(ss, m); }
  __shared__ float red[8];
  int l = t & 63, w = t >> 6;
  if (l == 0) { red[w*2] = s; red[w*2+1] = ss; }
  __syncthreads();
  s  = red[0] + red[2] + red[4] + red[6];
  ss = red[1] + red[3] + red[5] + red[7];
  float mean = s * (1.0f/1024.0f);
  float var  = ss * (1.0f/1024.0f) - mean*mean;
  float rstd = rsqrtf(var + 1e-5f);
  float4 gv = ((const float4*)g)[t];
  float4 bv = ((const float4*)be)[t];
  short4 o;
  o.x = (short)f2bf((v.x-mean)*rstd*gv.x + bv.x);
  o.y = (short)f2bf((v.y-mean)*rstd*gv.y + bv.y);
  o.z = (short)f2bf((v.z-mean)*rstd*gv.z + bv.z);
  o.w = (short)f2bf((v.w-mean)*rstd*gv.w + bv.w);
  *(short4*)(out + (long)row*1024 + t*4) = o;
}

// ---------------- bf16 GEMM, C = A[M,K] * Bt[N,K]^T, BK=64, double-buffered --
// Stage(t+1) issued BEFORE compute(t); ONE __syncthreads per iter (its implicit
// vmcnt(0) drains the prefetch after ~400cyc of MFMA instead of immediately).
// Proven correct in round 8; isolated here on the 377us baseline.
template<int EPI, int BM>
__global__ __launch_bounds__(256,2) void gemm_bt(
    const u16* __restrict__ A, const u16* __restrict__ Bt,
    int M, int N, int K,
    const float* __restrict__ bias,
    const float* __restrict__ gamma,
    const float* __restrict__ resid,
    float* __restrict__ outf,
    u16* __restrict__ outb0, u16* __restrict__ outb1)
{
  constexpr int MI = BM / 32;          // M fragments per wave
  __shared__ __align__(16) u16 at[2][BM*64];
  __shared__ __align__(16) u16 bt[2][128*64];
  int nwg = gridDim.x;
  int bidx = (blockIdx.x & 7) * (nwg >> 3) + (blockIdx.x >> 3);  // T1 XCD chunk
  int nb = N >> 7;
  int tm = bidx / nb, tn = bidx % nb;
  int m0 = tm * BM, n0 = tn << 7;
  int t = threadIdx.x, l = t & 63, w = t >> 6;
  int wr = (w >> 1) * (BM/2), wc = (w & 1) * 64;
  int fr = l & 15, fq = l >> 4;
  f32x4 acc[MI][4] = {};
  int rr = t >> 3;                // 0..31, staging row within 32-row round
  int cb = (t & 7) << 4;          // 0..112, staging 16B chunk
  const char* Ab = (const char*)A;
  const char* Bp = (const char*)Bt;
  long ld = (long)K * 2;

#define G_STAGE(s, kt) do {                                                        \
    _Pragma("unroll")                                                              \
    for (int c = 0; c < MI; c++) {                                                 \
      int row = c*32 + rr;                                                         \
      gload16(Ab + (long)(m0 + row)*ld + (long)(kt)*2 + (cb ^ ((row & 7) << 4)),   \
              (char*)at[s] + c*4096 + w*1024);                                     \
    }                                                                              \
    _Pragma("unroll")                                                              \
    for (int c = 0; c < 4; c++) {                                                  \
      int row = c*32 + rr;                                                         \
      gload16(Bp + (long)(n0 + row)*ld + (long)(kt)*2 + (cb ^ ((row & 7) << 4)),   \
              (char*)bt[s] + c*4096 + w*1024);                                     \
    }                                                                              \
  } while (0)

  G_STAGE(0, 0);
  __syncthreads();
  int cur = 0;
  for (int kt = 0; kt < K; kt += 64) {
    if (kt + 64 < K) G_STAGE(cur ^ 1, kt + 64);
    #pragma unroll
    for (int ka = 0; ka < 2; ka++) {
      bf16x8 af[MI], bfv[4];
      #pragma unroll
      for (int i = 0; i < MI; i++) {
        int ra = wr + i*16 + fr;
        af[i] = *(const bf16x8*)((const char*)at[cur] + ra*128 + ((ka*64 + fq*16) ^ ((ra & 7) << 4)));
      }
      #pragma unroll
      for (int j = 0; j < 4; j++) {
        int rb = wc + j*16 + fr;
        bfv[j] = *(const bf16x8*)((const char*)bt[cur] + rb*128 + ((ka*64 + fq*16) ^ ((rb & 7) << 4)));
      }
      #pragma unroll
      for (int i = 0; i < MI; i++)
        #pragma unroll
        for (int j = 0; j < 4; j++)
          acc[i][j] = MFMA16(af[i], bfv[j], acc[i][j]);
    }
    __syncthreads();      // implicit vmcnt(0): prefetch landed; buffers swap safe
    cur ^= 1;
  }
#undef G_STAGE
  #pragma unroll
  for (int i = 0; i < MI; i++) {
    #pragma unroll
    for (int j = 0; j < 4; j++) {
      #pragma unroll
      for (int r = 0; r < 4; r++) {
        int row = m0 + wr + i*16 + fq*4 + r;
        int col = n0 + wc + j*16 + fr;
        float v = acc[i][j][r];
        if constexpr (EPI == 0) {
          float qv = (v + bias[col]) * 0.18033688011112042f;  // (1/8)*log2(e)
          int b = row >> 10, lq = row & 1023, h = col >> 6, hd = col & 63;
          outb0[(((long)(b*16 + h)) << 16) + (lq << 6) + hd] = f2bf(qv);
        } else if constexpr (EPI == 1) {
          float u = v + bias[col];
          int b = row >> 11, p = row & 2047;
          if (col < 1024) {
            int h = col >> 6, hd = col & 63;
            outb0[(((long)((b*16 + h)*2048 + p)) << 6) + hd] = f2bf(u);
          } else {
            int c2 = col - 1024, h = c2 >> 6, hd = c2 & 63;
            outb1[(((long)((b*16 + h)*64 + hd)) << 11) + p] = f2bf(u);  // V^T
          }
        } else if constexpr (EPI == 2) {
          float gs = gamma[col]; gs = fminf(fmaxf(gs, -10.f), 10.f);
          long idx = (long)row*1024 + col;
          outf[idx] = resid[idx] + (v + bias[col]) * gs;
        } else if constexpr (EPI == 3) {
          float u = v + bias[col];
          float ge = 0.5f * u * (1.0f + erff(u * 0.70710678118654752f));
          outb0[(long)row*4096 + col] = f2bf(ge);
        } else {
          float gs = gamma[col]; gs = fminf(fmaxf(gs, -10.f), 10.f);
          long idx = (long)row*1024 + col;
          outf[idx] = resid[idx] + (v + bias[col]) * gs;
        }
      }
    }
  }
}

// ---------------- flash attention fwd (V staged in LDS once per block) -------
// KNOWN-GOOD round-9 version (75.6 us) -- unchanged.
__global__ __launch_bounds__(256, 4) void flash_fwd(
    const u16* __restrict__ q, const u16* __restrict__ k,
    const u16* __restrict__ vt, u16* __restrict__ ctx,
    float* __restrict__ ilout)
{
  __shared__ __align__(16) u16 ks[2][64*64];   // 16 KB dbuf K tile
  __shared__ __align__(16) u16 vs[64*64];      // 8 KB V tile [hd][64kv]
  __shared__ __align__(16) char ps[4*2304];    // per-wave Q-stage then P (16x144B)
  int nwg = gridDim.x;
  int bid = (blockIdx.x & 7) * (nwg >> 3) + (blockIdx.x >> 3);  // T1 XCD chunk
  int qt = bid & 15, h = (bid >> 4) & 15, b = bid >> 8;
  int q0 = qt << 6;
  int t = threadIdx.x, l = t & 63, w = t >> 6;
  int fr = l & 15, fq = l >> 4;
  const char* qb = (const char*)(q  + (((long)(b*16 + h)) << 16));
  const char* kb = (const char*)(k  + (((long)(b*16 + h)) << 17));
  const char* vb = (const char*)(vt + (((long)(b*16 + h)) << 17));
  char* psw = ps + w*2304;
  int rr = t >> 3;                // 0..31 block staging row
  int sc = (t & 7) << 4;          // 16B chunk within 128B row

  // prologue: stage K tile 0 + this wave's 16 Q rows
  #pragma unroll
  for (int c = 0; c < 2; c++) {
    int row = c*32 + rr;
    gload16(kb + (long)row*128 + (sc ^ ((row & 7) << 4)), (char*)ks[0] + c*4096 + w*1024);
  }
  {
    int qr = l >> 3;
    #pragma unroll
    for (int c = 0; c < 2; c++) {
      int row = c*8 + qr;
      gload16(qb + (long)(q0 + w*16 + row)*128 + (sc ^ ((row & 7) << 4)), psw + c*1024);
    }
  }
  asm volatile("s_waitcnt vmcnt(0)" ::: "memory");
  bf16x8 qf0 = *(const bf16x8*)(psw + fr*128 + ((fq*16) ^ ((fr & 7) << 4)));
  bf16x8 qf1 = *(const bf16x8*)(psw + fr*128 + ((64 + fq*16) ^ ((fr & 7) << 4)));
  asm volatile("s_waitcnt lgkmcnt(0)" ::: "memory");
  __builtin_amdgcn_s_barrier();
  asm volatile("" ::: "memory");

  f32x4 cacc[4] = {};
  f32x4 lrun = {0.f, 0.f, 0.f, 0.f};
  int cur = 0;
  for (int kt = 0; kt < 2048; kt += 64) {
    int notlast = (kt + 64 < 2048);
    // V-stage(t) FIRST (2 gloads/thread), pre-swizzled source (rule 21)
    #pragma unroll
    for (int c = 0; c < 2; c++) {
      int hd = c*32 + rr;
      gload16(vb + (long)hd*4096 + (long)kt*2 + (sc ^ ((hd & 7) << 4)),
              (char*)vs + c*4096 + w*1024);
    }
    // K-prefetch(t+1) SECOND
    if (notlast) {
      #pragma unroll
      for (int c = 0; c < 2; c++) {
        int row = c*32 + rr;
        gload16(kb + (long)(kt + 64 + row)*128 + (sc ^ ((row & 7) << 4)),
                (char*)ks[cur ^ 1] + c*4096 + w*1024);
      }
    }
    __builtin_amdgcn_sched_barrier(0);
    // QK(t) from ks[cur]
    const char* ksb = (const char*)ks[cur];
    f32x4 sf[4];
    __builtin_amdgcn_s_setprio(1);
    #pragma unroll
    for (int cf = 0; cf < 4; cf++) {
      int row = cf*16 + fr;
      bf16x8 kf0 = *(const bf16x8*)(ksb + row*128 + ((fq*16) ^ ((row & 7) << 4)));
      bf16x8 kf1 = *(const bf16x8*)(ksb + row*128 + ((64 + fq*16) ^ ((row & 7) << 4)));
      f32x4 a = {};
      a = MFMA16(qf0, kf0, a);
      sf[cf] = MFMA16(qf1, kf1, a);
    }
    __builtin_amdgcn_s_setprio(0);
    // softmax (m==0; log2e folded into q-proj) + P write (per-wave, stride 144)
    #pragma unroll
    for (int cf = 0; cf < 4; cf++)
      #pragma unroll
      for (int r = 0; r < 4; r++) {
        float pv = exp2f(sf[cf][r]);
        lrun[r] += pv;
        union { float f; unsigned int u; } pu; pu.f = pv;
        *(u16*)(psw + (fq*4 + r)*144 + ((cf*16 + fr) << 1)) = (u16)(pu.u >> 16);
      }
    // V landed? (own 2 V gloads retired; K's 2 still in flight)
    if (notlast) { asm volatile("s_waitcnt vmcnt(2)" ::: "memory"); }
    else         { asm volatile("s_waitcnt vmcnt(0)" ::: "memory"); }
    __builtin_amdgcn_s_barrier();
    asm volatile("" ::: "memory");
    // PV from V-LDS (swizzled b128 reads) ; P fragments from psw
    bf16x8 pa0 = *(const bf16x8*)(psw + fr*144 + fq*16);
    bf16x8 pa1 = *(const bf16x8*)(psw + fr*144 + 64 + fq*16);
    __builtin_amdgcn_s_setprio(1);
    #pragma unroll
    for (int cfd = 0; cfd < 4; cfd++) {
      int hd = cfd*16 + fr;
      bf16x8 vf0 = *(const bf16x8*)((const char*)vs + hd*128 + ((fq*16) ^ ((hd & 7) << 4)));
      bf16x8 vf1 = *(const bf16x8*)((const char*)vs + hd*128 + ((64 + fq*16) ^ ((hd & 7) << 4)));
      cacc[cfd] = MFMA16(pa0, vf0, cacc[cfd]);
      cacc[cfd] = MFMA16(pa1, vf1, cacc[cfd]);
    }
    __builtin_amdgcn_s_setprio(0);
    if (notlast) {
      asm volatile("s_waitcnt vmcnt(0)" ::: "memory");
      __builtin_amdgcn_s_barrier();
      asm volatile("" ::: "memory");
    }
    cur ^= 1;
  }
  float il4[4];
  #pragma unroll
  for (int r = 0; r < 4; r++) {
    float s = lrun[r];
    #pragma unroll
    for (int msk = 1; msk < 16; msk <<= 1) s += __shfl_xor(s, msk, 16);
    il4[r] = 1.0f / s;
  }
  #pragma unroll
  for (int cf = 0; cf < 4; cf++)
    #pragma unroll
    for (int r = 0; r < 4; r++) {
      int row = q0 + w*16 + fq*4 + r;
      int col = h*64 + cf*16 + fr;
      ctx[(long)(b*1024 + row)*1024 + col] = f2bf(cacc[cf][r] * il4[r]);
    }
  if (fr == 0) {
    #pragma unroll
    for (int r = 0; r < 4; r++) {
      int row = q0 + w*16 + fq*4 + r;
      long idx = (((long)(b*16 + h)) << 10) + row;
      ilout[idx] = il4[r];
    }
  }
}

// ---------------- attn mean over heads (GEMM-style, double-buffered) ---------
__global__ __launch_bounds__(256,2) void attn_mean(
    const u16* __restrict__ q, const u16* __restrict__ k,
    const float* __restrict__ il,
    float* __restrict__ out)
{
  __shared__ __align__(16) u16 qs[2][128*64];
  __shared__ __align__(16) u16 ks[2][128*64];
  __shared__ __align__(16) float ml[2][128];   // il for 128 q-rows
  int nwg = gridDim.x;
  int bid = (blockIdx.x & 7) * (nwg >> 3) + (blockIdx.x >> 3);  // T1 XCD chunk
  int kt = bid & 15, qt = (bid >> 4) & 7, b = bid >> 7;
  int q0 = qt << 7, k0 = kt << 7;
  int t = threadIdx.x, l = t & 63, w = t >> 6;
  int wr = (w >> 1) << 6, wc = (w & 1) << 6;
  int fr = l & 15, fq = l >> 4;
  int rr = t >> 3, cbb = (t & 7) << 4;
  const long bh = (long)b * 16;

#define AM_STAGE(hh, s) do {                                                        \
    const char* qb_ = (const char*)(q + ((bh + (hh)) << 16)) + (long)q0*128;        \
    const char* kb_ = (const char*)(k + ((bh + (hh)) << 17)) + (long)k0*128;        \
    _Pragma("unroll")                                                               \
    for (int c = 0; c < 4; c++) {                                                   \
      int row = c*32 + rr;                                                          \
      int sw = cbb ^ ((row & 7) << 4);                                              \
      gload16(qb_ + (long)row*128 + sw, (char*)qs[s] + c*4096 + w*1024);            \
      gload16(kb_ + (long)row*128 + sw, (char*)ks[s] + c*4096 + w*1024);            \
    }                                                                               \
    if (w == 0 && l < 32) {                                                         \
      gload16((const char*)(il + ((bh + (hh)) << 10) + q0) + l*16, (char*)ml[s]);   \
    }                                                                               \
  } while (0)

  AM_STAGE(0, 0);
  asm volatile("s_waitcnt vmcnt(0)" ::: "memory");
  __builtin_amdgcn_s_barrier();
  asm volatile("" ::: "memory");

  f32x4 macc[4][4] = {};
  for (int h = 0; h < 16; h++) {
    int cur = h & 1;
    if (h < 15) AM_STAGE(h + 1, cur ^ 1);
    const char* qsb = (const char*)qs[cur];
    const char* ksb = (const char*)ks[cur];
    const float* mlb = ml[cur];
    f32x4 ir4[4];
    #pragma unroll
    for (int i = 0; i < 4; i++)
      ir4[i] = *(const f32x4*)(mlb + wr + i*16 + fq*4);
    bf16x8 af[4][2], bf[4][2];
    #pragma unroll
    for (int i = 0; i < 4; i++) {
      int ra = wr + i*16 + fr;
      int rb = wc + i*16 + fr;
      af[i][0] = *(const bf16x8*)(qsb + ra*128 + ((fq*16) ^ ((ra & 7) << 4)));
      af[i][1] = *(const bf16x8*)(qsb + ra*128 + ((64 + fq*16) ^ ((ra & 7) << 4)));
      bf[i][0] = *(const bf16x8*)(ksb + rb*128 + ((fq*16) ^ ((rb & 7) << 4)));
      bf[i][1] = *(const bf16x8*)(ksb + rb*128 + ((64 + fq*16) ^ ((rb & 7) << 4)));
    }
    #pragma unroll
    for (int j = 0; j < 4; j++) {
      f32x4 sf[4];
      __builtin_amdgcn_s_setprio(1);
      #pragma unroll
      for (int i = 0; i < 4; i++) {
        f32x4 a = MFMA16(af[i][0], bf[j][0], {});
        sf[i] = MFMA16(af[i][1], bf[j][1], a);
      }
      __builtin_amdgcn_s_setprio(0);
      #pragma unroll
      for (int i = 0; i < 4; i++)
        #pragma unroll
        for (int r = 0; r < 4; r++)
          macc[i][j][r] += exp2f(sf[i][r]) * ir4[i][r];
    }
    asm volatile("s_waitcnt vmcnt(0)" ::: "memory");
    __builtin_amdgcn_s_barrier();
    asm volatile("" ::: "memory");
  }
#undef AM_STAGE
  #pragma unroll
  for (int i = 0; i < 4; i++)
    #pragma unroll
    for (int j = 0; j < 4; j++)
      #pragma unroll
      for (int r = 0; r < 4; r++) {
        int row = q0 + wr + i*16 + fq*4 + r;
        int col = k0 + wc + j*16 + fr;
        out[((long)(b*1024 + row) << 11) + col] = macc[i][j][r] * 0.0625f;
      }
}

extern "C" void kernel_launch(void* const* d_in, const int* in_sizes, int n_in,
                              void* d_out, int out_size, void* d_ws, size_t ws_size,
                              hipStream_t stream)
{
  (void)in_sizes; (void)n_in; (void)out_size; (void)ws_size;
  const float* tight = (const float*)d_in[0];
  const float* ctxt  = (const float*)d_in[1];
  const float* nbh   = (const float*)d_in[2];
  const float* lnqg  = (const float*)d_in[3];
  const float* lnqb  = (const float*)d_in[4];
  const float* lnkg  = (const float*)d_in[5];
  const float* lnkb  = (const float*)d_in[6];
  const float* wqkv  = (const float*)d_in[7];
  const float* bqkv  = (const float*)d_in[8];
  const float* wo    = (const float*)d_in[9];
  const float* bo    = (const float*)d_in[10];
  const float* cg    = (const float*)d_in[11];
  const float* lnfg  = (const float*)d_in[12];
  const float* lnfb  = (const float*)d_in[13];
  const float* w1    = (const float*)d_in[14];
  const float* b1    = (const float*)d_in[15];
  const float* w2    = (const float*)d_in[16];
  const float* b2    = (const float*)d_in[17];
  const float* fg    = (const float*)d_in[18];

  char* p = (char*)d_ws;
  u16* wqkv_bf = (u16*)p; p += 3072L*1024*2;
  u16* wo_bf   = (u16*)p; p += 1024L*1024*2;
  u16* w1_bf   = (u16*)p; p += 4096L*1024*2;
  u16* w2_bf   = (u16*)p; p += 1024L*4096*2;
  u16* qin_bf  = (u16*)p; p += 4096L*1024*2;
  u16* kvin_bf = (u16*)p; p += 8192L*1024*2;
  u16* q_bf    = (u16*)p; p += 4L*16*1024*64*2;
  u16* k_bf    = (u16*)p; p += 4L*16*2048*64*2;
  u16* vt_bf   = (u16*)p; p += 4L*16*64*2048*2;
  u16* ctx_bf  = (u16*)p; p += 4096L*1024*2;
  float* il_f  = (float*)p; p += 4L*16*1024*4;
  float* x_f   = (float*)p; p += 4096L*1024*4;
  u16* hln_bf  = (u16*)p; p += 4096L*1024*2;
  u16* gelu_bf = (u16*)p; p += 4096L*4096*2;

  float* x_out    = (float*)d_out;           // [4,1024,1024]
  float* mean_out = x_out + 4194304;         // [4,1024,2048]

  cvt_weights<<<12288, 256, 0, stream>>>(wqkv, wo, w1, w2, wqkv_bf, wo_bf, w1_bf, w2_bf);
  ln_kernel<0><<<4096, 256, 0, stream>>>(tight, nullptr, lnqg, lnqb, qin_bf);
  ln_kernel<1><<<8192, 256, 0, stream>>>(ctxt, nbh, lnkg, lnkb, kvin_bf);
  gemm_bt<0,64><<<512, 256, 0, stream>>>(qin_bf, wqkv_bf, 4096, 1024, 1024,
                                      bqkv, nullptr, nullptr, nullptr, q_bf, nullptr);
  gemm_bt<1,128><<<1024, 256, 0, stream>>>(kvin_bf, wqkv_bf + 1024L*1024, 8192, 2048, 1024,
                                       bqkv + 1024, nullptr, nullptr, nullptr, k_bf, vt_bf);
  flash_fwd<<<1024, 256, 0, stream>>>(q_bf, k_bf, vt_bf, ctx_bf, il_f);
  attn_mean<<<512, 256, 0, stream>>>(q_bf, k_bf, il_f, mean_out);
  gemm_bt<2,64><<<512, 256, 0, stream>>>(ctx_bf, wo_bf, 4096, 1024, 1024,
                                      bo, cg, tight, x_f, nullptr, nullptr);
  ln_kernel<0><<<4096, 256, 0, stream>>>(x_f, nullptr, lnfg, lnfb, hln_bf);
  gemm_bt<3,128><<<1024, 256, 0, stream>>>(hln_bf, w1_bf, 4096, 4096, 1024,
                                       b1, nullptr, nullptr, nullptr, gelu_bf, nullptr);
  gemm_bt<4,64><<<512, 256, 0, stream>>>(gelu_bf, w2_bf, 4096, 1024, 4096,
                                      b2, fg, x_f, x_out, nullptr, nullptr);
}